// Round 1
// baseline (492.391 us; speedup 1.0000x reference)
//
#include <hip/hip_runtime.h>
#include <math.h>

#define IN_DIM   128
#define OUT_DIM  128
#define FEAT_DIM 64

// ---------------------------------------------------------------------------
// z = h @ W_fc   [N,128] ; dz = feat @ W_dst  [N,128]
// One block (128 threads) per node; row staged in LDS; W columns read
// coalesced (W is [K][128] row-major, thread t reads column t).
// ---------------------------------------------------------------------------
__global__ void k_linear(const float* __restrict__ h, const float* __restrict__ feat,
                         const float* __restrict__ Wfc, const float* __restrict__ Wdst,
                         float* __restrict__ z, float* __restrict__ dz, int N) {
    int n = blockIdx.x;
    int t = threadIdx.x;                 // 0..127
    __shared__ float s_h[IN_DIM];
    __shared__ float s_f[FEAT_DIM];
    s_h[t] = h[(size_t)n * IN_DIM + t];
    if (t < FEAT_DIM) s_f[t] = feat[(size_t)n * FEAT_DIM + t];
    __syncthreads();
    float az = 0.f, ad = 0.f;
#pragma unroll 8
    for (int k = 0; k < IN_DIM; ++k)   az += s_h[k] * Wfc[(size_t)k * OUT_DIM + t];
#pragma unroll 8
    for (int k = 0; k < FEAT_DIM; ++k) ad += s_f[k] * Wdst[(size_t)k * OUT_DIM + t];
    z [(size_t)n * OUT_DIM + t] = az;
    dz[(size_t)n * OUT_DIM + t] = ad;
}

// ---------------------------------------------------------------------------
// CSR build: histogram by dst -> exclusive scan -> scatter edge ids
// ---------------------------------------------------------------------------
__global__ void k_hist(const int* __restrict__ dst, unsigned* __restrict__ counts, int E) {
    for (int i = blockIdx.x * blockDim.x + threadIdx.x; i < E; i += gridDim.x * blockDim.x)
        atomicAdd(&counts[dst[i]], 1u);
}

__global__ void k_scan(const unsigned* __restrict__ counts, unsigned* __restrict__ offsets, int N) {
    __shared__ unsigned s[1024];
    int t = threadIdx.x;
    int per = (N + 1023) / 1024;
    int b = t * per;
    int e_ = min(N, b + per);
    unsigned sum = 0;
    for (int i = b; i < e_; ++i) sum += counts[i];
    s[t] = sum;
    __syncthreads();
    for (int off = 1; off < 1024; off <<= 1) {
        unsigned v = (t >= off) ? s[t - off] : 0u;
        __syncthreads();
        s[t] += v;
        __syncthreads();
    }
    unsigned run = s[t] - sum;           // exclusive prefix of this thread's chunk
    for (int i = b; i < e_; ++i) { offsets[i] = run; run += counts[i]; }
    if (t == 1023) offsets[N] = s[1023];
}

__global__ void k_scatter(const int* __restrict__ dst, const unsigned* __restrict__ offsets,
                          unsigned* __restrict__ cursor, unsigned* __restrict__ csr, int E) {
    for (int i = blockIdx.x * blockDim.x + threadIdx.x; i < E; i += gridDim.x * blockDim.x) {
        int d = dst[i];
        unsigned pos = offsets[d] + atomicAdd(&cursor[d], 1u);
        csr[pos] = (unsigned)i;
    }
}

// ---------------------------------------------------------------------------
// e[i] = <z[src[i]], dz[dst[i]]> ; 32-lane group per edge, float4 per lane
// ---------------------------------------------------------------------------
__global__ void k_edge(const float* __restrict__ z, const float* __restrict__ dz,
                       const int* __restrict__ src, const int* __restrict__ dst,
                       float* __restrict__ e, int E) {
    int g    = threadIdx.x >> 5;         // 8 edge-groups per 256-thread block
    int lane = threadIdx.x & 31;
    long long edge = (long long)blockIdx.x * 8 + g;
    if (edge >= E) return;
    int s_ = src[edge], d_ = dst[edge];
    float4 a = ((const float4*)(z  + (size_t)s_ * OUT_DIM))[lane];
    float4 b = ((const float4*)(dz + (size_t)d_ * OUT_DIM))[lane];
    float v = a.x * b.x + a.y * b.y + a.z * b.z + a.w * b.w;
#pragma unroll
    for (int off = 16; off; off >>= 1) v += __shfl_xor(v, off, 32);
    if (lane == 0) e[edge] = v;
}

// ---------------------------------------------------------------------------
// Per-dst softmax + weighted aggregation. One 128-thread block per node.
// out[n] = (sum_e exp(e_e - m) * z[src_e]) / (sum_e exp(e_e - m))
// ---------------------------------------------------------------------------
__global__ void k_node(const float* __restrict__ z, const float* __restrict__ e,
                       const int* __restrict__ src, const unsigned* __restrict__ offsets,
                       const unsigned* __restrict__ csr, float* __restrict__ out, int N) {
    int n = blockIdx.x, t = threadIdx.x;  // 128 threads
    unsigned start = offsets[n];
    int deg = (int)(offsets[n + 1] - start);
    if (deg == 0) { out[(size_t)n * OUT_DIM + t] = 0.f; return; }

    __shared__ float s_red[128];
    __shared__ float s_ex[128];
    __shared__ int   s_src[128];

    // pass 1: block max of e over incoming edges
    float local = -INFINITY;
    for (int i = t; i < deg; i += 128) local = fmaxf(local, e[csr[start + i]]);
    s_red[t] = local;
    __syncthreads();
    for (int s = 64; s > 0; s >>= 1) {
        if (t < s) s_red[t] = fmaxf(s_red[t], s_red[t + s]);
        __syncthreads();
    }
    float m = s_red[0];

    // pass 2: chunked exp + weighted accumulate (thread t owns dim t)
    float acc = 0.f, denom = 0.f;
    for (int base = 0; base < deg; base += 128) {
        int idx = base + t;
        if (idx < deg) {
            unsigned eid = csr[start + idx];
            s_ex[t]  = __expf(e[eid] - m);
            s_src[t] = src[eid];
        }
        __syncthreads();
        int cnt = min(128, deg - base);
        for (int i = 0; i < cnt; ++i) {
            float w = s_ex[i];
            denom += w;
            acc   += w * z[(size_t)s_src[i] * OUT_DIM + t];
        }
        __syncthreads();
    }
    out[(size_t)n * OUT_DIM + t] = acc / denom;
}

// ---------------------------------------------------------------------------
extern "C" void kernel_launch(void* const* d_in, const int* in_sizes, int n_in,
                              void* d_out, int out_size, void* d_ws, size_t ws_size,
                              hipStream_t stream) {
    const float* h    = (const float*)d_in[0];
    const float* feat = (const float*)d_in[1];
    const float* Wfc  = (const float*)d_in[2];
    const float* Wdst = (const float*)d_in[3];
    const int*   src  = (const int*)d_in[4];
    const int*   dst  = (const int*)d_in[5];
    float*       out  = (float*)d_out;

    int N = in_sizes[0] / IN_DIM;
    int E = in_sizes[4];

    char* ws = (char*)d_ws;
    float*    z       = (float*)ws;    ws += (size_t)N * OUT_DIM * sizeof(float);
    float*    dz      = (float*)ws;    ws += (size_t)N * OUT_DIM * sizeof(float);
    float*    e       = (float*)ws;    ws += (size_t)E * sizeof(float);
    unsigned* counts  = (unsigned*)ws; ws += (size_t)N * sizeof(unsigned);
    unsigned* cursor  = (unsigned*)ws; ws += (size_t)N * sizeof(unsigned);
    unsigned* offsets = (unsigned*)ws; ws += (size_t)(N + 1) * sizeof(unsigned);
    unsigned* csr     = (unsigned*)ws;

    // zero counts + cursor (adjacent): one async memset, graph-capturable
    hipMemsetAsync(counts, 0, (size_t)2 * N * sizeof(unsigned), stream);

    k_linear <<<N, 128, 0, stream>>>(h, feat, Wfc, Wdst, z, dz, N);
    k_hist   <<<1024, 256, 0, stream>>>(dst, counts, E);
    k_scan   <<<1, 1024, 0, stream>>>(counts, offsets, N);
    k_scatter<<<1024, 256, 0, stream>>>(dst, offsets, cursor, csr, E);
    k_edge   <<<(E + 7) / 8, 256, 0, stream>>>(z, dz, src, dst, e, E);
    k_node   <<<N, 128, 0, stream>>>(z, e, src, offsets, csr, out, N);
}

// Round 2
// 321.121 us; speedup vs baseline: 1.5333x; 1.5333x over previous
//
#include <hip/hip_runtime.h>
#include <math.h>

#define IN_DIM   128
#define OUT_DIM  128
#define FEAT_DIM 64
#define NB       32     // nodes per k_linear block

// ---------------------------------------------------------------------------
// z = h @ W_fc ; dz = feat @ W_dst.  Register-blocked: 256 threads/block,
// 32 nodes/block. Thread = (col-group c: 4 cols) x (node-slot j0: 4 nodes).
// W rows streamed as float4 (L1/L2 resident across blocks), h/feat in LDS.
// ---------------------------------------------------------------------------
__global__ __launch_bounds__(256) void k_linear(
        const float* __restrict__ h, const float* __restrict__ feat,
        const float* __restrict__ Wfc, const float* __restrict__ Wdst,
        float* __restrict__ z, float* __restrict__ dz, int N) {
    int t  = threadIdx.x;        // 0..255
    int c  = t & 31;             // cols 4c..4c+3
    int j0 = t >> 5;             // 0..7 (node slots j0, j0+8, j0+16, j0+24)
    int n0 = blockIdx.x * NB;

    __shared__ float s_h[NB][IN_DIM];    // 16 KB
    __shared__ float s_f[NB][FEAT_DIM];  //  8 KB

    // stage tiles (row-clamped for the ragged last block)
    float4* s_h4 = (float4*)&s_h[0][0];
    for (int i = t; i < NB * (IN_DIM / 4); i += 256) {
        int row = i >> 5, col = i & 31;
        int n = min(n0 + row, N - 1);
        s_h4[i] = ((const float4*)(h + (size_t)n * IN_DIM))[col];
    }
    float4* s_f4 = (float4*)&s_f[0][0];
    for (int i = t; i < NB * (FEAT_DIM / 4); i += 256) {
        int row = i >> 4, col = i & 15;
        int n = min(n0 + row, N - 1);
        s_f4[i] = ((const float4*)(feat + (size_t)n * FEAT_DIM))[col];
    }
    __syncthreads();

    float4 az[4] = {{0,0,0,0},{0,0,0,0},{0,0,0,0},{0,0,0,0}};
    for (int k = 0; k < IN_DIM; ++k) {
        float4 w = ((const float4*)(Wfc + (size_t)k * OUT_DIM))[c];
#pragma unroll
        for (int jj = 0; jj < 4; ++jj) {
            float hv = s_h[j0 + jj * 8][k];
            az[jj].x += hv * w.x; az[jj].y += hv * w.y;
            az[jj].z += hv * w.z; az[jj].w += hv * w.w;
        }
    }
#pragma unroll
    for (int jj = 0; jj < 4; ++jj) {
        int n = n0 + j0 + jj * 8;
        if (n < N) ((float4*)(z + (size_t)n * OUT_DIM))[c] = az[jj];
    }

    float4 ad[4] = {{0,0,0,0},{0,0,0,0},{0,0,0,0},{0,0,0,0}};
    for (int k = 0; k < FEAT_DIM; ++k) {
        float4 w = ((const float4*)(Wdst + (size_t)k * OUT_DIM))[c];
#pragma unroll
        for (int jj = 0; jj < 4; ++jj) {
            float fv = s_f[j0 + jj * 8][k];
            ad[jj].x += fv * w.x; ad[jj].y += fv * w.y;
            ad[jj].z += fv * w.z; ad[jj].w += fv * w.w;
        }
    }
#pragma unroll
    for (int jj = 0; jj < 4; ++jj) {
        int n = n0 + j0 + jj * 8;
        if (n < N) ((float4*)(dz + (size_t)n * OUT_DIM))[c] = ad[jj];
    }
}

// ---------------------------------------------------------------------------
// CSR build: histogram by dst -> exclusive scan -> scatter SRC NODE IDS
// ---------------------------------------------------------------------------
__global__ void k_hist(const int* __restrict__ dst, unsigned* __restrict__ counts, int E) {
    for (int i = blockIdx.x * blockDim.x + threadIdx.x; i < E; i += gridDim.x * blockDim.x)
        atomicAdd(&counts[dst[i]], 1u);
}

__global__ void k_scan(const unsigned* __restrict__ counts, unsigned* __restrict__ offsets, int N) {
    __shared__ unsigned s[1024];
    int t = threadIdx.x;
    int per = (N + 1023) / 1024;
    int b = t * per;
    int e_ = min(N, b + per);
    unsigned sum = 0;
    for (int i = b; i < e_; ++i) sum += counts[i];
    s[t] = sum;
    __syncthreads();
    for (int off = 1; off < 1024; off <<= 1) {
        unsigned v = (t >= off) ? s[t - off] : 0u;
        __syncthreads();
        s[t] += v;
        __syncthreads();
    }
    unsigned run = s[t] - sum;
    for (int i = b; i < e_; ++i) { offsets[i] = run; run += counts[i]; }
    if (t == 1023) offsets[N] = s[1023];
}

__global__ void k_scatter(const int* __restrict__ dst, const int* __restrict__ src,
                          const unsigned* __restrict__ offsets,
                          unsigned* __restrict__ cursor, unsigned* __restrict__ csr, int E) {
    for (int i = blockIdx.x * blockDim.x + threadIdx.x; i < E; i += gridDim.x * blockDim.x) {
        int d = dst[i];
        unsigned pos = offsets[d] + atomicAdd(&cursor[d], 1u);
        csr[pos] = (unsigned)src[i];   // payload = source node id (skip edge indirection)
    }
}

// ---------------------------------------------------------------------------
// Fused attention + aggregation. One 128-thread block (2 waves) per node.
// Softmax shift-invariance => no max pass:
//   out[n] = sum_e exp(<z[s_e], dz[n]>) * z[s_e]  /  sum_e exp(...)
// Each wave owns alternating edges; z[src] row read ONCE per edge (float2/lane),
// used for both the dot (shfl_xor reduce) and the weighted accumulate.
// ---------------------------------------------------------------------------
__global__ __launch_bounds__(128) void k_node(
        const float* __restrict__ z, const float* __restrict__ dz,
        const unsigned* __restrict__ offsets, const unsigned* __restrict__ csr,
        float* __restrict__ out, int N) {
    int n = blockIdx.x, t = threadIdx.x;
    int lane = t & 63, wv = t >> 6;
    unsigned start = offsets[n];
    int deg = (int)(offsets[n + 1] - start);
    if (deg == 0) { out[(size_t)n * OUT_DIM + t] = 0.f; return; }

    float2 dzv = ((const float2*)(dz + (size_t)n * OUT_DIM))[lane];

    float acc0 = 0.f, acc1 = 0.f, denom = 0.f;
    for (int i = wv; i < deg; i += 2) {
        int s = (int)csr[start + i];
        float2 zv = ((const float2*)(z + (size_t)s * OUT_DIM))[lane];
        float p = zv.x * dzv.x + zv.y * dzv.y;
#pragma unroll
        for (int off = 32; off; off >>= 1) p += __shfl_xor(p, off);
        float w = __expf(p);
        denom += w;
        acc0 += w * zv.x;
        acc1 += w * zv.y;
    }

    __shared__ float s_acc[2][OUT_DIM];
    __shared__ float s_den[2];
    s_acc[wv][2 * lane]     = acc0;
    s_acc[wv][2 * lane + 1] = acc1;
    if (lane == 0) s_den[wv] = denom;
    __syncthreads();
    out[(size_t)n * OUT_DIM + t] =
        (s_acc[0][t] + s_acc[1][t]) / (s_den[0] + s_den[1]);
}

// ---------------------------------------------------------------------------
extern "C" void kernel_launch(void* const* d_in, const int* in_sizes, int n_in,
                              void* d_out, int out_size, void* d_ws, size_t ws_size,
                              hipStream_t stream) {
    const float* h    = (const float*)d_in[0];
    const float* feat = (const float*)d_in[1];
    const float* Wfc  = (const float*)d_in[2];
    const float* Wdst = (const float*)d_in[3];
    const int*   src  = (const int*)d_in[4];
    const int*   dst  = (const int*)d_in[5];
    float*       out  = (float*)d_out;

    int N = in_sizes[0] / IN_DIM;
    int E = in_sizes[4];

    char* ws = (char*)d_ws;
    float*    z       = (float*)ws;    ws += (size_t)N * OUT_DIM * sizeof(float);
    float*    dz      = (float*)ws;    ws += (size_t)N * OUT_DIM * sizeof(float);
    unsigned* counts  = (unsigned*)ws; ws += (size_t)N * sizeof(unsigned);
    unsigned* cursor  = (unsigned*)ws; ws += (size_t)N * sizeof(unsigned);
    unsigned* offsets = (unsigned*)ws; ws += (size_t)(N + 1) * sizeof(unsigned);
    unsigned* csr     = (unsigned*)ws;

    hipMemsetAsync(counts, 0, (size_t)2 * N * sizeof(unsigned), stream);

    k_linear <<<(N + NB - 1) / NB, 256, 0, stream>>>(h, feat, Wfc, Wdst, z, dz, N);
    k_hist   <<<1024, 256, 0, stream>>>(dst, counts, E);
    k_scan   <<<1, 1024, 0, stream>>>(counts, offsets, N);
    k_scatter<<<1024, 256, 0, stream>>>(dst, src, offsets, cursor, csr, E);
    k_node   <<<N, 128, 0, stream>>>(z, dz, offsets, csr, out, N);
}

// Round 3
// 267.892 us; speedup vs baseline: 1.8380x; 1.1987x over previous
//
#include <hip/hip_runtime.h>
#include <math.h>

#define IN_DIM   128
#define OUT_DIM  128
#define FEAT_DIM 64
#define NB       64     // nodes per k_linear block

// ---------------------------------------------------------------------------
// z = h @ W_fc ; dz = feat @ W_dst.  256 threads/block, 64 nodes/block.
// Thread = (col-group c: 4 cols) x (node-slot j0: 8 nodes). W rows streamed
// as float4 (L2-resident), h/feat tiles in LDS. Tail: fused dst-histogram.
// ---------------------------------------------------------------------------
__global__ __launch_bounds__(256) void k_linear(
        const float* __restrict__ h, const float* __restrict__ feat,
        const float* __restrict__ Wfc, const float* __restrict__ Wdst,
        float* __restrict__ z, float* __restrict__ dz, int N,
        const int* __restrict__ dst, unsigned* __restrict__ counts, int E) {
    int t  = threadIdx.x;        // 0..255
    int c  = t & 31;             // cols 4c..4c+3
    int j0 = t >> 5;             // 0..7 (node slots j0 + 8*jj)
    int n0 = blockIdx.x * NB;

    __shared__ float s_h[NB][IN_DIM];    // 32 KB
    __shared__ float s_f[NB][FEAT_DIM];  // 16 KB

    float4* s_h4 = (float4*)&s_h[0][0];
    for (int i = t; i < NB * (IN_DIM / 4); i += 256) {
        int row = i >> 5, col = i & 31;
        int n = min(n0 + row, N - 1);
        s_h4[i] = ((const float4*)(h + (size_t)n * IN_DIM))[col];
    }
    float4* s_f4 = (float4*)&s_f[0][0];
    for (int i = t; i < NB * (FEAT_DIM / 4); i += 256) {
        int row = i >> 4, col = i & 15;
        int n = min(n0 + row, N - 1);
        s_f4[i] = ((const float4*)(feat + (size_t)n * FEAT_DIM))[col];
    }
    __syncthreads();

    float4 a[8];
#pragma unroll
    for (int jj = 0; jj < 8; ++jj) a[jj] = make_float4(0.f, 0.f, 0.f, 0.f);
    for (int k = 0; k < IN_DIM; ++k) {
        float4 w = ((const float4*)(Wfc + (size_t)k * OUT_DIM))[c];
#pragma unroll
        for (int jj = 0; jj < 8; ++jj) {
            float hv = s_h[j0 + jj * 8][k];
            a[jj].x += hv * w.x; a[jj].y += hv * w.y;
            a[jj].z += hv * w.z; a[jj].w += hv * w.w;
        }
    }
#pragma unroll
    for (int jj = 0; jj < 8; ++jj) {
        int n = n0 + j0 + jj * 8;
        if (n < N) ((float4*)(z + (size_t)n * OUT_DIM))[c] = a[jj];
    }

#pragma unroll
    for (int jj = 0; jj < 8; ++jj) a[jj] = make_float4(0.f, 0.f, 0.f, 0.f);
    for (int k = 0; k < FEAT_DIM; ++k) {
        float4 w = ((const float4*)(Wdst + (size_t)k * OUT_DIM))[c];
#pragma unroll
        for (int jj = 0; jj < 8; ++jj) {
            float fv = s_f[j0 + jj * 8][k];
            a[jj].x += fv * w.x; a[jj].y += fv * w.y;
            a[jj].z += fv * w.z; a[jj].w += fv * w.w;
        }
    }
#pragma unroll
    for (int jj = 0; jj < 8; ++jj) {
        int n = n0 + j0 + jj * 8;
        if (n < N) ((float4*)(dz + (size_t)n * OUT_DIM))[c] = a[jj];
    }

    // fused dst-histogram (overlaps across blocks with the GEMM above)
    int stride = gridDim.x * 256;
    for (int i = blockIdx.x * 256 + t; i < E; i += stride)
        atomicAdd(&counts[dst[i]], 1u);
}

// ---------------------------------------------------------------------------
// exclusive scan of counts -> offsets (single block)
// ---------------------------------------------------------------------------
__global__ void k_scan(const unsigned* __restrict__ counts, unsigned* __restrict__ offsets, int N) {
    __shared__ unsigned s[1024];
    int t = threadIdx.x;
    int per = (N + 1023) / 1024;
    int b = t * per;
    int e_ = min(N, b + per);
    unsigned sum = 0;
    for (int i = b; i < e_; ++i) sum += counts[i];
    s[t] = sum;
    __syncthreads();
    for (int off = 1; off < 1024; off <<= 1) {
        unsigned v = (t >= off) ? s[t - off] : 0u;
        __syncthreads();
        s[t] += v;
        __syncthreads();
    }
    unsigned run = s[t] - sum;
    for (int i = b; i < e_; ++i) { offsets[i] = run; run += counts[i]; }
    if (t == 1023) offsets[N] = s[1023];
}

__global__ void k_scatter(const int* __restrict__ dst, const int* __restrict__ src,
                          const unsigned* __restrict__ offsets,
                          unsigned* __restrict__ cursor, unsigned* __restrict__ csr, int E) {
    for (int i = blockIdx.x * blockDim.x + threadIdx.x; i < E; i += gridDim.x * blockDim.x) {
        int d = dst[i];
        unsigned pos = offsets[d] + atomicAdd(&cursor[d], 1u);
        csr[pos] = (unsigned)src[i];   // payload = source node id
    }
}

// ---------------------------------------------------------------------------
// Fused attention + aggregation. One 128-thread block per node, 4 groups of
// 32 lanes; each group unrolls 4 edges deep (16 z-rows in flight per block).
//   out[n] = sum_e exp(<z[s_e], dz[n]>) * z[s_e]  /  sum_e exp(...)
// ---------------------------------------------------------------------------
__device__ __forceinline__ float dot4(float4 a, float4 b) {
    return a.x * b.x + a.y * b.y + a.z * b.z + a.w * b.w;
}
__device__ __forceinline__ float red32(float p) {
#pragma unroll
    for (int off = 16; off; off >>= 1) p += __shfl_xor(p, off);
    return p;
}

__global__ __launch_bounds__(128) void k_node(
        const float* __restrict__ z, const float* __restrict__ dz,
        const unsigned* __restrict__ offsets, const unsigned* __restrict__ csr,
        float* __restrict__ out, int N) {
    int n = blockIdx.x, t = threadIdx.x;
    int lane = t & 31, g = t >> 5;       // 4 groups of 32 lanes
    unsigned start = offsets[n];
    int deg = (int)(offsets[n + 1] - start);
    if (deg == 0) { out[(size_t)n * OUT_DIM + t] = 0.f; return; }

    float4 dzv = ((const float4*)(dz + (size_t)n * OUT_DIM))[lane];

    float4 acc = make_float4(0.f, 0.f, 0.f, 0.f);
    float denom = 0.f;

    int i = g;
    for (; i + 12 < deg; i += 16) {      // 4 edges in flight per group
        int s0 = (int)csr[start + i];
        int s1 = (int)csr[start + i + 4];
        int s2 = (int)csr[start + i + 8];
        int s3 = (int)csr[start + i + 12];
        float4 z0 = ((const float4*)(z + (size_t)s0 * OUT_DIM))[lane];
        float4 z1 = ((const float4*)(z + (size_t)s1 * OUT_DIM))[lane];
        float4 z2 = ((const float4*)(z + (size_t)s2 * OUT_DIM))[lane];
        float4 z3 = ((const float4*)(z + (size_t)s3 * OUT_DIM))[lane];
        float p0 = red32(dot4(z0, dzv));
        float p1 = red32(dot4(z1, dzv));
        float p2 = red32(dot4(z2, dzv));
        float p3 = red32(dot4(z3, dzv));
        float w0 = __expf(p0), w1 = __expf(p1), w2 = __expf(p2), w3 = __expf(p3);
        denom += (w0 + w1) + (w2 + w3);
        acc.x += w0 * z0.x + w1 * z1.x + w2 * z2.x + w3 * z3.x;
        acc.y += w0 * z0.y + w1 * z1.y + w2 * z2.y + w3 * z3.y;
        acc.z += w0 * z0.z + w1 * z1.z + w2 * z2.z + w3 * z3.z;
        acc.w += w0 * z0.w + w1 * z1.w + w2 * z2.w + w3 * z3.w;
    }
    for (; i < deg; i += 4) {            // remainder
        int s0 = (int)csr[start + i];
        float4 z0 = ((const float4*)(z + (size_t)s0 * OUT_DIM))[lane];
        float w0 = __expf(red32(dot4(z0, dzv)));
        denom += w0;
        acc.x += w0 * z0.x; acc.y += w0 * z0.y;
        acc.z += w0 * z0.z; acc.w += w0 * z0.w;
    }

    __shared__ float s_acc[4][OUT_DIM];
    __shared__ float s_den[4];
    ((float4*)&s_acc[g][0])[lane] = acc;
    if (lane == 0) s_den[g] = denom;
    __syncthreads();
    float r = (s_acc[0][t] + s_acc[1][t]) + (s_acc[2][t] + s_acc[3][t]);
    float d = (s_den[0] + s_den[1]) + (s_den[2] + s_den[3]);
    out[(size_t)n * OUT_DIM + t] = r / d;
}

// ---------------------------------------------------------------------------
extern "C" void kernel_launch(void* const* d_in, const int* in_sizes, int n_in,
                              void* d_out, int out_size, void* d_ws, size_t ws_size,
                              hipStream_t stream) {
    const float* h    = (const float*)d_in[0];
    const float* feat = (const float*)d_in[1];
    const float* Wfc  = (const float*)d_in[2];
    const float* Wdst = (const float*)d_in[3];
    const int*   src  = (const int*)d_in[4];
    const int*   dst  = (const int*)d_in[5];
    float*       out  = (float*)d_out;

    int N = in_sizes[0] / IN_DIM;
    int E = in_sizes[4];

    char* ws = (char*)d_ws;
    float*    z       = (float*)ws;    ws += (size_t)N * OUT_DIM * sizeof(float);
    float*    dz      = (float*)ws;    ws += (size_t)N * OUT_DIM * sizeof(float);
    unsigned* counts  = (unsigned*)ws; ws += (size_t)N * sizeof(unsigned);
    unsigned* cursor  = (unsigned*)ws; ws += (size_t)N * sizeof(unsigned);
    unsigned* offsets = (unsigned*)ws; ws += (size_t)(N + 1) * sizeof(unsigned);
    unsigned* csr     = (unsigned*)ws;

    hipMemsetAsync(counts, 0, (size_t)2 * N * sizeof(unsigned), stream);

    int nblin = (N + NB - 1) / NB;
    k_linear <<<nblin, 256, 0, stream>>>(h, feat, Wfc, Wdst, z, dz, N, dst, counts, E);
    k_scan   <<<1, 1024, 0, stream>>>(counts, offsets, N);
    k_scatter<<<1024, 256, 0, stream>>>(dst, src, offsets, cursor, csr, E);
    k_node   <<<N, 128, 0, stream>>>(z, dz, offsets, csr, out, N);
}